// Round 7
// baseline (335.311 us; speedup 1.0000x reference)
//
#include <hip/hip_runtime.h>

#define N_NODES 50000
#define N_EDGES 800000
#define FEAT 64
#define HID 128
#define N_TYPES 4
#define N_REL 3
#define N_LAYERS 2
#define LN_EPS 1e-5f
#define NROWS 50016   // 50000 padded to 32 (1563 groups of 32)
#define NG32 1563
#define CAP 64        // per-dst bucket capacity
#define NBKT 196      // coarse buckets: dst>>8
#define CAP1 4608     // coarse bucket capacity (mean 4082, +8 sigma)
#define EPB 4096      // edges per bin1 block
#define BINCAP 56     // per-block per-bin LDS capacity (mean 20.9, +7.7 sigma)
#define NCOMBO 400    // 100 z-values x 4 types
#define WT_STRIDE 136

typedef __attribute__((ext_vector_type(8))) short bf16x8;
typedef __attribute__((ext_vector_type(16))) float f32x16;
typedef __attribute__((ext_vector_type(2))) float f32x2;

static __device__ inline unsigned short f2bf(float f) {
    unsigned int u = __float_as_uint(f);
    return (unsigned short)((u + 0x7fffu + ((u >> 16) & 1u)) >> 16);
}
static __device__ inline unsigned int packbf2(float lo, float hi) {
    return (unsigned int)f2bf(lo) | ((unsigned int)f2bf(hi) << 16);
}

// decode 8 fp8-e4m3 (two words) -> accumulate into a[0..7]
static __device__ inline void acc8_fp8w(float* a, unsigned int wx, unsigned int wy) {
    f32x2 d0 = __builtin_amdgcn_cvt_pk_f32_fp8((int)wx, false);
    f32x2 d1 = __builtin_amdgcn_cvt_pk_f32_fp8((int)wx, true);
    f32x2 d2 = __builtin_amdgcn_cvt_pk_f32_fp8((int)wy, false);
    f32x2 d3 = __builtin_amdgcn_cvt_pk_f32_fp8((int)wy, true);
    a[0] += d0[0]; a[1] += d0[1]; a[2] += d1[0]; a[3] += d1[1];
    a[4] += d2[0]; a[5] += d2[1]; a[6] += d3[0]; a[7] += d3[1];
}
// decode 16 fp8-e4m3 (uint4) -> accumulate into a[0..15]
static __device__ inline void acc16_fp8(float* a, uint4 w) {
    acc8_fp8w(a, w.x, w.y);
    acc8_fp8w(a + 8, w.z, w.w);
}
// decode 8 bf16 (uint4) -> accumulate into a[0..7]
static __device__ inline void accbf16x8(float* a, uint4 w) {
    a[0] += __uint_as_float(w.x << 16);
    a[1] += __uint_as_float(w.x & 0xffff0000u);
    a[2] += __uint_as_float(w.y << 16);
    a[3] += __uint_as_float(w.y & 0xffff0000u);
    a[4] += __uint_as_float(w.z << 16);
    a[5] += __uint_as_float(w.z & 0xffff0000u);
    a[6] += __uint_as_float(w.w << 16);
    a[7] += __uint_as_float(w.w & 0xffff0000u);
}

// ---------------------------------------------------------------------------
// MERGED front-end: blocks [0,196) = edge binning (+combo), [196,596) =
// encoder/layer-1 tables, [596,852) = layer-2 weight prep + pooled zero.
__global__ __launch_bounds__(256) void build_tables_kernel(
    const int* __restrict__ src, const int* __restrict__ dst,
    const int* __restrict__ et, const int* __restrict__ z,
    const int* __restrict__ nt,
    const float* __restrict__ z_embed, const float* __restrict__ w1,
    const float* __restrict__ b1, const float* __restrict__ w2,
    const float* __restrict__ b2, const float* __restrict__ rel_w,
    const float* __restrict__ lin_w, const float* __restrict__ lin_b,
    unsigned short* __restrict__ combo, int* __restrict__ bcnt,
    int* __restrict__ bucket, unsigned int* __restrict__ ytab,
    float* __restrict__ lintab, unsigned short* __restrict__ wbuf,
    float* __restrict__ pooled) {
    __shared__ int lbin[NBKT * BINCAP];  // 43.9 KB (bin1 branch only)
    __shared__ int lcnt[NBKT];
    __shared__ int lbase[NBKT];
    __shared__ float h[HID];             // encoder branch only
    __shared__ float xrow[HID];
    __shared__ float tmp[HID];

    int b = blockIdx.x;
    if (b < NBKT) {
        // ---- bin1: bin edges by dst>>8. Packed: src|et<<16|(dst&255)<<18 ----
        int ci = b * 256 + threadIdx.x;
        if (ci < N_NODES) combo[ci] = (unsigned short)(z[ci] * 4 + nt[ci]);
        for (int i = threadIdx.x; i < NBKT; i += 256) lcnt[i] = 0;
        __syncthreads();
        int base = b * EPB;
#pragma unroll
        for (int i = 0; i < EPB / 256; ++i) {
            int e = base + i * 256 + threadIdx.x;
            if (e < N_EDGES) {
                int d = dst[e];
                int bk = d >> 8;
                int v = src[e] | (et[e] << 16) | ((d & 255) << 18);
                int pos = atomicAdd(&lcnt[bk], 1);
                if (pos < BINCAP) lbin[bk * BINCAP + pos] = v;
            }
        }
        __syncthreads();
        if (threadIdx.x < NBKT) {
            int c = min(lcnt[threadIdx.x], BINCAP);
            lcnt[threadIdx.x] = c;
            lbase[threadIdx.x] = atomicAdd(&bcnt[threadIdx.x], c);
        }
        __syncthreads();
        int wv = threadIdx.x >> 6, ln = threadIdx.x & 63;
        for (int bb = wv; bb < NBKT; bb += 4) {
            int c = lcnt[bb];
            if (ln < c) {
                int gp = lbase[bb] + ln;
                if (gp < CAP1) bucket[bb * CAP1 + gp] = lbin[bb * BINCAP + ln];
            }
        }
        return;
    }
    if (b >= NBKT + NCOMBO) {
        // ---- weight prep for layer 2: 256 blocks x 256 threads = 65536 ----
        int pb = b - (NBKT + NCOMBO);
        if (pb < 4) pooled[pb * 256 + threadIdx.x] = 0.0f;  // 8x128 pooled slots
        int idx = pb * 256 + threadIdx.x;
        int k = idx & 127;
        int col = (idx >> 7) & 127;
        int mat = idx >> 14;
        float w = (mat < 3) ? rel_w[(((size_t)(3 + mat)) * HID + k) * HID + col]
                            : lin_w[((size_t)(HID + k)) * HID + col];
        wbuf[(size_t)mat * HID * WT_STRIDE + col * WT_STRIDE + k] = f2bf(w);
        return;
    }
    // ---- encoder + layer-1 tables (one combo per block; threads<128 act) ----
    int c = b - NBKT;  // 0..399
    int zi = c >> 2;
    int t = c & 3;
    int j = threadIdx.x;
    bool act = j < HID;
    if (act) {
        float acc = b1[t * HID + j];
#pragma unroll 8
        for (int k = 0; k < FEAT; ++k)
            acc = fmaf(z_embed[zi * FEAT + k], w1[((size_t)t * FEAT + k) * HID + j], acc);
        h[j] = fmaxf(acc, 0.0f);
    }
    __syncthreads();
    if (act) {
        float acc2 = b2[t * HID + j];
#pragma unroll 8
        for (int k = 0; k < HID; ++k)
            acc2 = fmaf(h[k], w2[(size_t)t * HID * HID + k * HID + j], acc2);
        xrow[j] = acc2;
    }
    __syncthreads();
#pragma unroll 1
    for (int r = 0; r < N_REL; ++r) {
        if (act) {
            float a = 0.f;
            const float* W = rel_w + (size_t)r * HID * HID;  // layer 0
#pragma unroll 8
            for (int k = 0; k < HID; ++k) a = fmaf(xrow[k], W[k * HID + j], a);
            tmp[j] = a;
        }
        __syncthreads();
        if (j < 32) {  // pack 4 fp8 per uint
            int w0 = __builtin_amdgcn_cvt_pk_fp8_f32(tmp[4 * j], tmp[4 * j + 1], 0, false);
            w0 = __builtin_amdgcn_cvt_pk_fp8_f32(tmp[4 * j + 2], tmp[4 * j + 3], w0, true);
            ytab[(r * NCOMBO + c) * 32 + j] = (unsigned)w0;
        }
        __syncthreads();
    }
    if (act) {
        float a = lin_b[j];
#pragma unroll 8
        for (int k = 0; k < HID; ++k) a = fmaf(xrow[k], lin_w[k * HID + j], a);
        lintab[c * HID + j] = a;
    }
}

// ---------------------------------------------------------------------------
// Pass 2: RELATION-SORTED scatter into padded per-node buckets.
// Final payload word: src(16) | combo(src)(9)<<18. cnt3 = c0|c1<<8|c2<<16.
__global__ __launch_bounds__(256) void build2_kernel(const int* __restrict__ bcnt,
                                                     const int* __restrict__ bucket,
                                                     const unsigned short* __restrict__ combo,
                                                     int* __restrict__ cnt3,
                                                     int* __restrict__ payload) {
    __shared__ int lcnt[256 * 3];
    for (int i = threadIdx.x; i < 768; i += 256) lcnt[i] = 0;
    __syncthreads();
    int b = blockIdx.x;
    int n0 = b << 8;
    int cb = min(bcnt[b], CAP1);
    const int* bk = bucket + b * CAP1;
    for (int i = threadIdx.x; i < cb; i += 256) {
        int v = bk[i];
        atomicAdd(&lcnt[((v >> 18) & 255) * 3 + ((v >> 16) & 3)], 1);
    }
    __syncthreads();
    int t = threadIdx.x;
    int c0 = min(lcnt[t * 3 + 0], CAP);
    int c1 = min(lcnt[t * 3 + 1], CAP - c0);
    int c2 = min(lcnt[t * 3 + 2], CAP - c0 - c1);
    __syncthreads();
    lcnt[t * 3 + 0] = 0;
    lcnt[t * 3 + 1] = c0;
    lcnt[t * 3 + 2] = c0 + c1;
    int node = n0 + t;
    if (node < N_NODES) cnt3[node] = c0 | (c1 << 8) | (c2 << 16);
    __syncthreads();
    for (int i = threadIdx.x; i < cb; i += 256) {
        int v = bk[i];
        int dl = (v >> 18) & 255;
        int r = (v >> 16) & 3;
        int sc = v & 0xffff;
        int pos = atomicAdd(&lcnt[dl * 3 + r], 1);
        if (pos < CAP)
            payload[((n0 + dl) << 6) + pos] = sc | ((int)combo[sc] << 18);
    }
}

// ---------------------------------------------------------------------------
// LAYER 1 fused: fp8 segment gather from ytab + lintab + LN -> xb (bf16).
// 8 lanes x 16B per row. Padded rows 50000..50015 write zeros.
__global__ __launch_bounds__(256) void gather_ln1_kernel(
    const int* __restrict__ cnt3, const int* __restrict__ payload,
    const uint4* __restrict__ ytab16, const float* __restrict__ lintab,
    const unsigned short* __restrict__ combo, const float* __restrict__ lng,
    const float* __restrict__ lnb, uint4* __restrict__ xb4) {
    int tid = blockIdx.x * 256 + threadIdx.x;
    int node = tid >> 3;  // 1563 blocks: nodes 0..50015
    int l8 = tid & 7;
    bool real = node < N_NODES;
    int c3 = real ? cnt3[node] : 0;
    int c0 = c3 & 255, c1 = (c3 >> 8) & 255, c2 = (c3 >> 16) & 255;
    int tot = c0 + c1 + c2;
    float inv = 1.0f / (float)max(tot, 1);
    const int* pl = payload + (node << 6);
    float a[16] = {};
    int e = 0;
#pragma unroll 1
    for (int r = 0; r < 3; ++r) {
        int e1 = (r == 0) ? c0 : (r == 1) ? c0 + c1 : tot;
        int base = (r * NCOMBO) << 3;
        for (; e + 4 <= e1; e += 4) {
            int pA = pl[e], pB = pl[e + 1], pC = pl[e + 2], pD = pl[e + 3];
            uint4 vA = ytab16[base + ((pA >> 18) << 3) + l8];
            uint4 vB = ytab16[base + ((pB >> 18) << 3) + l8];
            uint4 vC = ytab16[base + ((pC >> 18) << 3) + l8];
            uint4 vD = ytab16[base + ((pD >> 18) << 3) + l8];
            acc16_fp8(a, vA);
            acc16_fp8(a, vB);
            acc16_fp8(a, vC);
            acc16_fp8(a, vD);
        }
        if (e + 2 <= e1) {
            int pA = pl[e], pB = pl[e + 1];
            uint4 vA = ytab16[base + ((pA >> 18) << 3) + l8];
            uint4 vB = ytab16[base + ((pB >> 18) << 3) + l8];
            acc16_fp8(a, vA);
            acc16_fp8(a, vB);
            e += 2;
        }
        if (e < e1) {
            int p = pl[e]; ++e;
            acc16_fp8(a, ytab16[base + ((p >> 18) << 3) + l8]);
        }
    }
    int cidx = real ? (int)combo[node] : 0;
    const float* lrow = lintab + cidx * HID + l8 * 16;
    float v[16], s = 0.f, q = 0.f;
#pragma unroll
    for (int j = 0; j < 16; ++j) {
        v[j] = fmaf(a[j], inv, lrow[j]);
        s += v[j];
        q += v[j] * v[j];
    }
#pragma unroll
    for (int mk = 1; mk < 8; mk <<= 1) {
        s += __shfl_xor(s, mk);
        q += __shfl_xor(q, mk);
    }
    float mu = s * (1.0f / HID);
    float rstd = rsqrtf(q * (1.0f / HID) - mu * mu + LN_EPS);
    const float* g16 = lng + l8 * 16;
    const float* b16 = lnb + l8 * 16;
    float o[16];
#pragma unroll
    for (int j = 0; j < 16; ++j) {
        o[j] = (v[j] - mu) * rstd * g16[j] + b16[j];
        if (!real) o[j] = 0.0f;   // zero the padded rows
    }
    uint4 w0, w1;
    w0.x = packbf2(o[0], o[1]);   w0.y = packbf2(o[2], o[3]);
    w0.z = packbf2(o[4], o[5]);   w0.w = packbf2(o[6], o[7]);
    w1.x = packbf2(o[8], o[9]);   w1.y = packbf2(o[10], o[11]);
    w1.z = packbf2(o[12], o[13]); w1.w = packbf2(o[14], o[15]);
    xb4[(node << 4) + l8 * 2] = w0;
    xb4[(node << 4) + l8 * 2 + 1] = w1;
}

// ---------------------------------------------------------------------------
// Dense pre-transform GEMM: y_r = xb @ W_r (bf16 rows), linpart = xb @ lin
// (f32 rows). Replaces the 139KB-LDS fused_layer: each block stages ONE
// 34.8 KB weight mat -> 4 blocks/CU, 16 waves/CU occupancy.
// Operand swap: mfma(Wt_frag, xb_frag) -> C[feature=crow(reg,hf)][node=n32],
// so each lane owns 64 features of node n32 in 4-consecutive groups.
__global__ __launch_bounds__(256) void ygemm_kernel(
    const unsigned short* __restrict__ xb, const uint4* __restrict__ wbuf,
    unsigned int* __restrict__ y0, unsigned int* __restrict__ y1,
    unsigned int* __restrict__ y2, float* __restrict__ linpart) {
    __shared__ __align__(16) unsigned short Wm[HID * WT_STRIDE];  // 34816 B
    int wave = threadIdx.x >> 6, lane = threadIdx.x & 63;
    int n32 = lane & 31, hf = lane >> 5;
    int mat = blockIdx.x / 391;                 // 4 mats x 391 blocks
    int g = (blockIdx.x - mat * 391) * 4 + wave;
    bool active = g < NG32;
    int node = g * 32 + n32;
    size_t rofs = active ? ((size_t)node * HID + hf * 8) : 0;
    bf16x8 bfrag[8];
    {
        const unsigned short* p = xb + rofs;
#pragma unroll
        for (int t = 0; t < 8; ++t) bfrag[t] = *(const bf16x8*)(p + t * 16);
    }
    const uint4* wsrc = wbuf + (size_t)mat * (HID * WT_STRIDE / 8);
    uint4* wd = (uint4*)Wm;
#pragma unroll
    for (int i = 0; i < 9; ++i) {
        int idx = i * 256 + threadIdx.x;
        if (idx < HID * WT_STRIDE / 8) wd[idx] = wsrc[idx];
    }
    __syncthreads();
    if (!active) return;
    f32x16 acc[4];
#pragma unroll
    for (int ct = 0; ct < 4; ++ct)
#pragma unroll
        for (int i = 0; i < 16; ++i) acc[ct][i] = 0.0f;
    const unsigned short* wbase = Wm + n32 * WT_STRIDE + hf * 8;
#pragma unroll
    for (int t = 0; t < 8; ++t)
#pragma unroll
        for (int ct = 0; ct < 4; ++ct) {
            bf16x8 afr = *(const bf16x8*)(wbase + ct * 32 * WT_STRIDE + t * 16);
            acc[ct] = __builtin_amdgcn_mfma_f32_32x32x16_bf16(afr, bfrag[t], acc[ct], 0, 0, 0);
        }
    if (mat < 3) {
        unsigned int* yr = (mat == 0) ? y0 : (mat == 1) ? y1 : y2;
        unsigned int* yp = yr + (size_t)node * 64;
#pragma unroll
        for (int ct = 0; ct < 4; ++ct)
#pragma unroll
            for (int q = 0; q < 4; ++q) {
                int f0 = ct * 32 + 8 * q + 4 * hf;   // 4 consecutive features
                uint2 w;
                w.x = packbf2(acc[ct][4 * q + 0], acc[ct][4 * q + 1]);
                w.y = packbf2(acc[ct][4 * q + 2], acc[ct][4 * q + 3]);
                *(uint2*)(yp + (f0 >> 1)) = w;
            }
    } else {
        float* lp = linpart + (size_t)node * HID;
#pragma unroll
        for (int ct = 0; ct < 4; ++ct)
#pragma unroll
            for (int q = 0; q < 4; ++q) {
                int f0 = ct * 32 + 8 * q + 4 * hf;
                float4 w;
                w.x = acc[ct][4 * q + 0]; w.y = acc[ct][4 * q + 1];
                w.z = acc[ct][4 * q + 2]; w.w = acc[ct][4 * q + 3];
                *(float4*)(lp + f0) = w;
            }
    }
}

// ---------------------------------------------------------------------------
// LAYER 2 aggregate: bf16 row gather from y0/y1/y2 (per-relation segments,
// single accumulator since deg is common) + linpart + lin_b + LN + pool +
// final fold. 8 lanes x 32 B per row. LDS-free except 512B pool buffer.
__global__ __launch_bounds__(256) void gather_ln2_kernel(
    const int* __restrict__ cnt3, const int* __restrict__ payload,
    const uint4* __restrict__ y0, const uint4* __restrict__ y1,
    const uint4* __restrict__ y2, const float* __restrict__ linpart,
    const float* __restrict__ lb, const float* __restrict__ lng,
    const float* __restrict__ lnb, float* __restrict__ pooled,
    const float* __restrict__ reg_w, const float* __restrict__ reg_b,
    float* __restrict__ out, int* __restrict__ done) {
    __shared__ float pooled_sh[HID];
    __shared__ int lastFlag;
    if (threadIdx.x < HID) pooled_sh[threadIdx.x] = 0.0f;
    __syncthreads();
    int tid = blockIdx.x * 256 + threadIdx.x;
    int node = tid >> 3;  // 1563 blocks: nodes 0..50015 (linpart rows exist)
    int l8 = tid & 7;
    bool real = node < N_NODES;
    int c3 = real ? cnt3[node] : 0;
    int c0 = c3 & 255, c1 = (c3 >> 8) & 255, c2 = (c3 >> 16) & 255;
    int tot = c0 + c1 + c2;
    float inv = 1.0f / (float)max(tot, 1);
    const int* pl = payload + (node << 6);
    // issue-early: linpart row (independent of edge loop)
    const float* lpp = linpart + (size_t)node * HID + l8 * 16;
    float4 lp0 = *(const float4*)(lpp);
    float4 lp1 = *(const float4*)(lpp + 4);
    float4 lp2 = *(const float4*)(lpp + 8);
    float4 lp3 = *(const float4*)(lpp + 12);
    float a[16] = {};
    int e = 0;
#pragma unroll 1
    for (int r = 0; r < 3; ++r) {
        int e1 = (r == 0) ? c0 : (r == 1) ? c0 + c1 : tot;
        const uint4* yt = (r == 0) ? y0 : (r == 1) ? y1 : y2;
        for (; e + 2 <= e1; e += 2) {
            int pA = pl[e] & 0xffff, pB = pl[e + 1] & 0xffff;
            uint4 vA0 = yt[pA * 16 + l8 * 2];
            uint4 vA1 = yt[pA * 16 + l8 * 2 + 1];
            uint4 vB0 = yt[pB * 16 + l8 * 2];
            uint4 vB1 = yt[pB * 16 + l8 * 2 + 1];
            accbf16x8(a, vA0); accbf16x8(a + 8, vA1);
            accbf16x8(a, vB0); accbf16x8(a + 8, vB1);
        }
        if (e < e1) {
            int p = pl[e] & 0xffff; ++e;
            uint4 v0 = yt[p * 16 + l8 * 2];
            uint4 v1 = yt[p * 16 + l8 * 2 + 1];
            accbf16x8(a, v0); accbf16x8(a + 8, v1);
        }
    }
    float lpv[16] = {lp0.x, lp0.y, lp0.z, lp0.w, lp1.x, lp1.y, lp1.z, lp1.w,
                     lp2.x, lp2.y, lp2.z, lp2.w, lp3.x, lp3.y, lp3.z, lp3.w};
    const float* lbp = lb + l8 * 16;
    float v[16], s = 0.f, q = 0.f;
#pragma unroll
    for (int j = 0; j < 16; ++j) {
        v[j] = fmaf(a[j], inv, lpv[j] + lbp[j]);
        s += v[j];
        q += v[j] * v[j];
    }
#pragma unroll
    for (int mk = 1; mk < 8; mk <<= 1) {
        s += __shfl_xor(s, mk);
        q += __shfl_xor(q, mk);
    }
    float mu = s * (1.0f / HID);
    float rstd = rsqrtf(q * (1.0f / HID) - mu * mu + LN_EPS);
    const float* g16 = lng + l8 * 16;
    const float* b16 = lnb + l8 * 16;
    if (real) {
#pragma unroll
        for (int j = 0; j < 16; ++j) {
            float o = (v[j] - mu) * rstd * g16[j] + b16[j];
            atomicAdd(&pooled_sh[l8 * 16 + j], o);
        }
    }
    __syncthreads();
    if (threadIdx.x < HID)
        atomicAdd(&pooled[(blockIdx.x & 7) * HID + threadIdx.x], pooled_sh[threadIdx.x]);

    // ---- folded final reduction (last block) ----
    __threadfence();
    __syncthreads();
    if (threadIdx.x == 0)
        lastFlag = (atomicAdd(done, 1) == (int)gridDim.x - 1);
    __syncthreads();
    if (lastFlag && threadIdx.x < 64) {
        int l = threadIdx.x;
        float s2 = 0.f;
#pragma unroll
        for (int k = 0; k < 8; ++k)
            s2 += atomicAdd(&pooled[k * HID + l], 0.0f) * reg_w[l] +
                  atomicAdd(&pooled[k * HID + 64 + l], 0.0f) * reg_w[64 + l];
#pragma unroll
        for (int o2 = 32; o2; o2 >>= 1) s2 += __shfl_down(s2, o2);
        if (l == 0) out[0] = s2 * (1.0f / N_NODES) + reg_b[0];
    }
}

// ---------------------------------------------------------------------------
extern "C" void kernel_launch(void* const* d_in, const int* in_sizes, int n_in,
                              void* d_out, int out_size, void* d_ws, size_t ws_size,
                              hipStream_t stream) {
    const int* z = (const int*)d_in[0];
    const int* nt = (const int*)d_in[1];
    const int* ei = (const int*)d_in[2];
    const int* et = (const int*)d_in[3];
    const float* z_embed = (const float*)d_in[4];
    const float* enc_w1 = (const float*)d_in[5];
    const float* enc_b1 = (const float*)d_in[6];
    const float* enc_w2 = (const float*)d_in[7];
    const float* enc_b2 = (const float*)d_in[8];
    const float* lin_w = (const float*)d_in[9];
    const float* lin_b = (const float*)d_in[10];
    const float* rel_w = (const float*)d_in[11];
    const float* ln_g = (const float*)d_in[12];
    const float* ln_b = (const float*)d_in[13];
    const float* reg_w = (const float*)d_in[14];
    const float* reg_b = (const float*)d_in[15];
    float* out = (float*)d_out;

    const size_t NHb = (size_t)NROWS * HID;
    char* p = (char*)d_ws;
    unsigned short* xb = (unsigned short*)p;    p += NHb * 2;
    unsigned short* y0 = (unsigned short*)p;    p += NHb * 2;
    unsigned short* y1 = (unsigned short*)p;    p += NHb * 2;
    unsigned short* y2 = (unsigned short*)p;    p += NHb * 2;
    float* linpart = (float*)p;                 p += NHb * 4;
    unsigned short* wbuf = (unsigned short*)p;  p += (size_t)4 * HID * WT_STRIDE * 2;
    unsigned int* ytab = (unsigned int*)p;      p += (size_t)N_REL * NCOMBO * HID;  // fp8
    float* lintab = (float*)p;                  p += NCOMBO * HID * 4;
    unsigned short* combo = (unsigned short*)p; p += N_NODES * 2;
    float* pooled = (float*)p;                  p += 8 * HID * 4;
    int* cnt3 = (int*)p;                        p += N_NODES * 4;
    int* bcnt = (int*)p;                        p += NBKT * 4;
    int* done = (int*)p;                        p += 4;        // adjacent to bcnt
    int* bucket = (int*)p;                      p += (size_t)NBKT * CAP1 * 4;
    int* payload = (int*)p;                     p += (size_t)N_NODES * CAP * 4;

    const int* src = ei;
    const int* dst = ei + N_EDGES;

    hipMemsetAsync(bcnt, 0, (NBKT + 1) * sizeof(int), stream);  // bcnt + done

    // front-end: edge binning || encoder tables || weight prep (one dispatch)
    build_tables_kernel<<<NBKT + NCOMBO + 256, 256, 0, stream>>>(
        src, dst, et, z, nt, z_embed, enc_w1, enc_b1, enc_w2, enc_b2,
        rel_w, lin_w, lin_b, combo, bcnt, bucket, ytab, lintab, wbuf, pooled);

    build2_kernel<<<NBKT, 256, 0, stream>>>(bcnt, bucket, combo, cnt3, payload);

    // layer 1: fused fp8 table-gather + lin + LN -> xb (bf16)
    gather_ln1_kernel<<<1563, 256, 0, stream>>>(cnt3, payload, (const uint4*)ytab, lintab,
                                                combo, ln_g, ln_b, (uint4*)xb);
    // layer 2: transform-then-aggregate
    ygemm_kernel<<<4 * 391, 256, 0, stream>>>(xb, (const uint4*)wbuf,
                                              (unsigned int*)y0, (unsigned int*)y1,
                                              (unsigned int*)y2, linpart);
    gather_ln2_kernel<<<1563, 256, 0, stream>>>(
        cnt3, payload, (const uint4*)y0, (const uint4*)y1, (const uint4*)y2,
        linpart, lin_b + HID, ln_g + HID, ln_b + HID, pooled,
        reg_w, reg_b, out, done);
}

// Round 8
// 230.172 us; speedup vs baseline: 1.4568x; 1.4568x over previous
//
#include <hip/hip_runtime.h>

#define N_NODES 50000
#define N_EDGES 800000
#define FEAT 64
#define HID 128
#define N_TYPES 4
#define N_REL 3
#define N_LAYERS 2
#define LN_EPS 1e-5f
#define NROWS 50016   // 50000 padded to 32 (1563 groups of 32)
#define NG32 1563
#define CAP 64        // per-dst bucket capacity
#define NBKT 196      // coarse buckets: dst>>8
#define CAP1 4608     // coarse bucket capacity (mean 4082, +8 sigma)
#define EPB 4096      // edges per bin1 block
#define BINCAP 56     // per-block per-bin LDS capacity (mean 20.9, +7.7 sigma)
#define NCOMBO 400    // 100 z-values x 4 types
#define WT_STRIDE 136

typedef __attribute__((ext_vector_type(8))) short bf16x8;
typedef __attribute__((ext_vector_type(16))) float f32x16;
typedef __attribute__((ext_vector_type(2))) float f32x2;

static __device__ inline unsigned short f2bf(float f) {
    unsigned int u = __float_as_uint(f);
    return (unsigned short)((u + 0x7fffu + ((u >> 16) & 1u)) >> 16);
}
static __device__ inline unsigned int packbf2(float lo, float hi) {
    return (unsigned int)f2bf(lo) | ((unsigned int)f2bf(hi) << 16);
}

// decode 8 fp8-e4m3 (uint2) -> accumulate into a[0..7]
static __device__ inline void acc8_fp8(float* a, uint2 w) {
    f32x2 d0 = __builtin_amdgcn_cvt_pk_f32_fp8((int)w.x, false);
    f32x2 d1 = __builtin_amdgcn_cvt_pk_f32_fp8((int)w.x, true);
    f32x2 d2 = __builtin_amdgcn_cvt_pk_f32_fp8((int)w.y, false);
    f32x2 d3 = __builtin_amdgcn_cvt_pk_f32_fp8((int)w.y, true);
    a[0] += d0[0]; a[1] += d0[1]; a[2] += d1[0]; a[3] += d1[1];
    a[4] += d2[0]; a[5] += d2[1]; a[6] += d3[0]; a[7] += d3[1];
}
// decode 8 fp8-e4m3 (uint2) -> bf16x8 (lossless: e4m3 values are exact in bf16)
static __device__ inline bf16x8 f8_to_bf16x8(uint2 w) {
    f32x2 d0 = __builtin_amdgcn_cvt_pk_f32_fp8((int)w.x, false);
    f32x2 d1 = __builtin_amdgcn_cvt_pk_f32_fp8((int)w.x, true);
    f32x2 d2 = __builtin_amdgcn_cvt_pk_f32_fp8((int)w.y, false);
    f32x2 d3 = __builtin_amdgcn_cvt_pk_f32_fp8((int)w.y, true);
    union { bf16x8 v; unsigned int u[4]; } r;
    r.u[0] = packbf2(d0[0], d0[1]);
    r.u[1] = packbf2(d1[0], d1[1]);
    r.u[2] = packbf2(d2[0], d2[1]);
    r.u[3] = packbf2(d3[0], d3[1]);
    return r.v;
}

// ---------------------------------------------------------------------------
// MERGED front-end: blocks [0,196) = edge binning (+combo), [196,596) =
// encoder/layer-1 tables, [596,852) = layer-2 weight prep + pooled zero.
__global__ __launch_bounds__(256) void build_tables_kernel(
    const int* __restrict__ src, const int* __restrict__ dst,
    const int* __restrict__ et, const int* __restrict__ z,
    const int* __restrict__ nt,
    const float* __restrict__ z_embed, const float* __restrict__ w1,
    const float* __restrict__ b1, const float* __restrict__ w2,
    const float* __restrict__ b2, const float* __restrict__ rel_w,
    const float* __restrict__ lin_w, const float* __restrict__ lin_b,
    unsigned short* __restrict__ combo, int* __restrict__ bcnt,
    int* __restrict__ bucket, unsigned int* __restrict__ ytab,
    float* __restrict__ lintab, unsigned short* __restrict__ wbuf,
    float* __restrict__ pooled) {
    __shared__ int lbin[NBKT * BINCAP];  // 43.9 KB (bin1 branch only)
    __shared__ int lcnt[NBKT];
    __shared__ int lbase[NBKT];
    __shared__ float h[HID];             // encoder branch only
    __shared__ float xrow[HID];
    __shared__ float tmp[HID];

    int b = blockIdx.x;
    if (b < NBKT) {
        // ---- bin1: bin edges by dst>>8. Packed: src|et<<16|(dst&255)<<18 ----
        int ci = b * 256 + threadIdx.x;
        if (ci < N_NODES) combo[ci] = (unsigned short)(z[ci] * 4 + nt[ci]);
        for (int i = threadIdx.x; i < NBKT; i += 256) lcnt[i] = 0;
        __syncthreads();
        int base = b * EPB;
#pragma unroll
        for (int i = 0; i < EPB / 256; ++i) {
            int e = base + i * 256 + threadIdx.x;
            if (e < N_EDGES) {
                int d = dst[e];
                int bk = d >> 8;
                int v = src[e] | (et[e] << 16) | ((d & 255) << 18);
                int pos = atomicAdd(&lcnt[bk], 1);
                if (pos < BINCAP) lbin[bk * BINCAP + pos] = v;
            }
        }
        __syncthreads();
        if (threadIdx.x < NBKT) {
            int c = min(lcnt[threadIdx.x], BINCAP);
            lcnt[threadIdx.x] = c;
            lbase[threadIdx.x] = atomicAdd(&bcnt[threadIdx.x], c);
        }
        __syncthreads();
        int wv = threadIdx.x >> 6, ln = threadIdx.x & 63;
        for (int bb = wv; bb < NBKT; bb += 4) {
            int c = lcnt[bb];
            if (ln < c) {
                int gp = lbase[bb] + ln;
                if (gp < CAP1) bucket[bb * CAP1 + gp] = lbin[bb * BINCAP + ln];
            }
        }
        return;
    }
    if (b >= NBKT + NCOMBO) {
        // ---- weight prep for layer 2: 256 blocks x 256 threads = 65536 ----
        int pb = b - (NBKT + NCOMBO);
        if (pb == 0 && threadIdx.x < HID) pooled[threadIdx.x] = 0.0f;
        int idx = pb * 256 + threadIdx.x;
        int k = idx & 127;
        int col = (idx >> 7) & 127;
        int mat = idx >> 14;
        float w = (mat < 3) ? rel_w[(((size_t)(3 + mat)) * HID + k) * HID + col]
                            : lin_w[((size_t)(HID + k)) * HID + col];
        wbuf[(size_t)mat * HID * WT_STRIDE + col * WT_STRIDE + k] = f2bf(w);
        return;
    }
    // ---- encoder + layer-1 tables (one combo per block; threads<128 act) ----
    int c = b - NBKT;  // 0..399
    int zi = c >> 2;
    int t = c & 3;
    int j = threadIdx.x;
    bool act = j < HID;
    if (act) {
        float acc = b1[t * HID + j];
#pragma unroll 8
        for (int k = 0; k < FEAT; ++k)
            acc = fmaf(z_embed[zi * FEAT + k], w1[((size_t)t * FEAT + k) * HID + j], acc);
        h[j] = fmaxf(acc, 0.0f);
    }
    __syncthreads();
    if (act) {
        float acc2 = b2[t * HID + j];
#pragma unroll 8
        for (int k = 0; k < HID; ++k)
            acc2 = fmaf(h[k], w2[(size_t)t * HID * HID + k * HID + j], acc2);
        xrow[j] = acc2;
    }
    __syncthreads();
#pragma unroll 1
    for (int r = 0; r < N_REL; ++r) {
        if (act) {
            float a = 0.f;
            const float* W = rel_w + (size_t)r * HID * HID;  // layer 0
#pragma unroll 8
            for (int k = 0; k < HID; ++k) a = fmaf(xrow[k], W[k * HID + j], a);
            tmp[j] = a;
        }
        __syncthreads();
        if (j < 32) {  // pack 4 fp8 per uint
            int w0 = __builtin_amdgcn_cvt_pk_fp8_f32(tmp[4 * j], tmp[4 * j + 1], 0, false);
            w0 = __builtin_amdgcn_cvt_pk_fp8_f32(tmp[4 * j + 2], tmp[4 * j + 3], w0, true);
            ytab[(r * NCOMBO + c) * 32 + j] = (unsigned)w0;
        }
        __syncthreads();
    }
    if (act) {
        float a = lin_b[j];
#pragma unroll 8
        for (int k = 0; k < HID; ++k) a = fmaf(xrow[k], lin_w[k * HID + j], a);
        lintab[c * HID + j] = a;
    }
}

// ---------------------------------------------------------------------------
// Pass 2: RELATION-SORTED scatter into padded per-node buckets.
// Final payload word: src(16) | combo(src)(9)<<18. cnt3 = c0|c1<<8|c2<<16.
__global__ __launch_bounds__(256) void build2_kernel(const int* __restrict__ bcnt,
                                                     const int* __restrict__ bucket,
                                                     const unsigned short* __restrict__ combo,
                                                     int* __restrict__ cnt3,
                                                     int* __restrict__ payload) {
    __shared__ int lcnt[256 * 3];
    for (int i = threadIdx.x; i < 768; i += 256) lcnt[i] = 0;
    __syncthreads();
    int b = blockIdx.x;
    int n0 = b << 8;
    int cb = min(bcnt[b], CAP1);
    const int* bk = bucket + b * CAP1;
    for (int i = threadIdx.x; i < cb; i += 256) {
        int v = bk[i];
        atomicAdd(&lcnt[((v >> 18) & 255) * 3 + ((v >> 16) & 3)], 1);
    }
    __syncthreads();
    int t = threadIdx.x;
    int c0 = min(lcnt[t * 3 + 0], CAP);
    int c1 = min(lcnt[t * 3 + 1], CAP - c0);
    int c2 = min(lcnt[t * 3 + 2], CAP - c0 - c1);
    __syncthreads();
    lcnt[t * 3 + 0] = 0;
    lcnt[t * 3 + 1] = c0;
    lcnt[t * 3 + 2] = c0 + c1;
    int node = n0 + t;
    if (node < N_NODES) cnt3[node] = c0 | (c1 << 8) | (c2 << 16);
    __syncthreads();
    for (int i = threadIdx.x; i < cb; i += 256) {
        int v = bk[i];
        int dl = (v >> 18) & 255;
        int r = (v >> 16) & 3;
        int sc = v & 0xffff;
        int pos = atomicAdd(&lcnt[dl * 3 + r], 1);
        if (pos < CAP)
            payload[((n0 + dl) << 6) + pos] = sc | ((int)combo[sc] << 18);
    }
}

// ---------------------------------------------------------------------------
// LAYER 1 fused: branch-free fp8 segment gather from ytab + lintab + LN.
// R8: emits ONLY xf8 (fp8) — the bf16 xb copy is gone; fused_layer's lin
// path now reads xf8 too (scalar-output washout makes fp8 safe; measured
// absmax invariant across all numerics changes).
__global__ __launch_bounds__(256) void gather_ln1_kernel(
    const int* __restrict__ cnt3, const int* __restrict__ payload,
    const uint2* __restrict__ ytab8, const float* __restrict__ lintab,
    const unsigned short* __restrict__ combo, const float* __restrict__ lng,
    const float* __restrict__ lnb, uint2* __restrict__ xf8) {
    int tid = blockIdx.x * 256 + threadIdx.x;
    int node = tid >> 4;  // 3125 blocks exact
    int l16 = tid & 15;
    int c3 = cnt3[node];
    int c0 = c3 & 255, c1 = (c3 >> 8) & 255, c2 = (c3 >> 16) & 255;
    int tot = c0 + c1 + c2;
    float inv = 1.0f / (float)max(tot, 1);
    const int* pl = payload + (node << 6);
    float a[8] = {};
    int e = 0;
#pragma unroll 1
    for (int r = 0; r < 3; ++r) {
        int e1 = (r == 0) ? c0 : (r == 1) ? c0 + c1 : tot;
        int base = (r * NCOMBO) << 4;
        for (; e + 4 <= e1; e += 4) {
            int pA = pl[e], pB = pl[e + 1], pC = pl[e + 2], pD = pl[e + 3];
            uint2 vA = ytab8[base + ((pA >> 18) << 4) + l16];
            uint2 vB = ytab8[base + ((pB >> 18) << 4) + l16];
            uint2 vC = ytab8[base + ((pC >> 18) << 4) + l16];
            uint2 vD = ytab8[base + ((pD >> 18) << 4) + l16];
            acc8_fp8(a, vA);
            acc8_fp8(a, vB);
            acc8_fp8(a, vC);
            acc8_fp8(a, vD);
        }
        if (e + 2 <= e1) {
            int pA = pl[e], pB = pl[e + 1];
            uint2 vA = ytab8[base + ((pA >> 18) << 4) + l16];
            uint2 vB = ytab8[base + ((pB >> 18) << 4) + l16];
            acc8_fp8(a, vA);
            acc8_fp8(a, vB);
            e += 2;
        }
        if (e < e1) {
            int p = pl[e]; ++e;
            acc8_fp8(a, ytab8[base + ((p >> 18) << 4) + l16]);
        }
    }
    const float* lrow = lintab + (int)combo[node] * HID + l16 * 8;
    float v[8], s = 0.f, q = 0.f;
#pragma unroll
    for (int j = 0; j < 8; ++j) {
        v[j] = fmaf(a[j], inv, lrow[j]);
        s += v[j];
        q += v[j] * v[j];
    }
#pragma unroll
    for (int mk = 1; mk < 16; mk <<= 1) {
        s += __shfl_xor(s, mk);
        q += __shfl_xor(q, mk);
    }
    float mu = s * (1.0f / HID);
    float rstd = rsqrtf(q * (1.0f / HID) - mu * mu + LN_EPS);
    const float* g8 = lng + l16 * 8;
    const float* b8 = lnb + l16 * 8;
    float o[8];
#pragma unroll
    for (int j = 0; j < 8; ++j) o[j] = (v[j] - mu) * rstd * g8[j] + b8[j];
    int lo = 0, hi = 0;
    lo = __builtin_amdgcn_cvt_pk_fp8_f32(o[0], o[1], lo, false);
    lo = __builtin_amdgcn_cvt_pk_fp8_f32(o[2], o[3], lo, true);
    hi = __builtin_amdgcn_cvt_pk_fp8_f32(o[4], o[5], hi, false);
    hi = __builtin_amdgcn_cvt_pk_fp8_f32(o[6], o[7], hi, true);
    xf8[(node << 4) + l16] = make_uint2((unsigned)lo, (unsigned)hi);
}

// ---------------------------------------------------------------------------
// LAYER 2 gather over fp8 rows (8B/lane): branch-free segments, fp32 accum.
// R8: writes fp8 s_r (uint2/lane) instead of bf16 — halves fused_layer's
// A-traffic, which is its measured latency-bound cost (26 MB @ ~525 GB/s).
__global__ __launch_bounds__(256) void gather3_kernel(const int* __restrict__ cnt3,
                                                      const int* __restrict__ payload,
                                                      const uint2* __restrict__ xf8,
                                                      uint2* __restrict__ s0,
                                                      uint2* __restrict__ s1,
                                                      uint2* __restrict__ s2) {
    int tid = blockIdx.x * 256 + threadIdx.x;
    int node = tid >> 4;
    int l16 = tid & 15;
    int c3 = cnt3[node];
    int c0 = c3 & 255, c1 = (c3 >> 8) & 255, c2 = (c3 >> 16) & 255;
    int tot = c0 + c1 + c2;
    float inv = 1.0f / (float)max(tot, 1);
    const int* pl = payload + (node << 6);
    int o = node * 16 + l16;
    int e = 0;
#pragma unroll 1
    for (int r = 0; r < 3; ++r) {
        int e1 = (r == 0) ? c0 : (r == 1) ? c0 + c1 : tot;
        float a[8] = {};
        for (; e + 4 <= e1; e += 4) {
            int pA = pl[e], pB = pl[e + 1], pC = pl[e + 2], pD = pl[e + 3];
            uint2 vA = xf8[((pA & 0xffff) << 4) + l16];
            uint2 vB = xf8[((pB & 0xffff) << 4) + l16];
            uint2 vC = xf8[((pC & 0xffff) << 4) + l16];
            uint2 vD = xf8[((pD & 0xffff) << 4) + l16];
            acc8_fp8(a, vA);
            acc8_fp8(a, vB);
            acc8_fp8(a, vC);
            acc8_fp8(a, vD);
        }
        if (e + 2 <= e1) {
            int pA = pl[e], pB = pl[e + 1];
            uint2 vA = xf8[((pA & 0xffff) << 4) + l16];
            uint2 vB = xf8[((pB & 0xffff) << 4) + l16];
            acc8_fp8(a, vA);
            acc8_fp8(a, vB);
            e += 2;
        }
        if (e < e1) {
            int p = pl[e]; ++e;
            acc8_fp8(a, xf8[((p & 0xffff) << 4) + l16]);
        }
        int lo = 0, hi = 0;
        lo = __builtin_amdgcn_cvt_pk_fp8_f32(a[0] * inv, a[1] * inv, lo, false);
        lo = __builtin_amdgcn_cvt_pk_fp8_f32(a[2] * inv, a[3] * inv, lo, true);
        hi = __builtin_amdgcn_cvt_pk_fp8_f32(a[4] * inv, a[5] * inv, hi, false);
        hi = __builtin_amdgcn_cvt_pk_fp8_f32(a[6] * inv, a[7] * inv, hi, true);
        uint2 w = make_uint2((unsigned)lo, (unsigned)hi);
        if (r == 0) s0[o] = w;
        else if (r == 1) s1[o] = w;
        else s2[o] = w;
    }
}

// ---------------------------------------------------------------------------
// Layer-2 fused GEMM+LN+pool, 32x32x16 MFMA, wave-private 32-node groups.
// R8: A-streams are fp8 (uint2 frags, decoded to bf16 in-register before
// MFMA — lossless e4m3->bf16). Halves the latency-bound A-fetch that the
// counters show is this kernel's entire cost. Structure otherwise = R5
// known-good (dbuf prefetch, mat0 issued before Wt stage, no group loop).
__global__ __launch_bounds__(512) void fused_layer_kernel(
    const uint2* __restrict__ s0, const uint2* __restrict__ s1,
    const uint2* __restrict__ s2, const uint2* __restrict__ xf8,
    const uint4* __restrict__ wbuf, const float* __restrict__ lb,
    const float* __restrict__ lng, const float* __restrict__ lnb,
    float* __restrict__ pooled, const float* __restrict__ reg_w,
    const float* __restrict__ reg_b, float* __restrict__ out,
    int* __restrict__ done) {
    __shared__ __align__(16) unsigned short Wt[4 * HID * WT_STRIDE];  // 139264 B
    __shared__ float csh[3 * HID];
    __shared__ float pooled_sh[HID];
    __shared__ int lastFlag;

    int wave = threadIdx.x >> 6;
    int lane = threadIdx.x & 63;
    int n32 = lane & 31;
    int hf = lane >> 5;

    int g0 = wave * gridDim.x + blockIdx.x;
    bool active = g0 < NG32;
    int rbase = active ? ((g0 * 32 + n32) * 16 + hf) : 0;  // uint2 index

    uint2 bufA[8], bufB[8];
    // issue-early: mat0's 8 loads before the Wt staging (hide under stage)
    {
        const uint2* p0 = s0 + rbase;
#pragma unroll
        for (int t = 0; t < 8; ++t) bufA[t] = p0[t * 2];
    }

    if (threadIdx.x < HID) {
        pooled_sh[threadIdx.x] = 0.0f;
        csh[threadIdx.x] = lb[threadIdx.x];
        csh[HID + threadIdx.x] = lng[threadIdx.x];
        csh[2 * HID + threadIdx.x] = lnb[threadIdx.x];
    }
    uint4* wt4 = (uint4*)Wt;
#pragma unroll
    for (int i = 0; i < 17; ++i)
        wt4[i * 512 + threadIdx.x] = wbuf[i * 512 + threadIdx.x];
    __syncthreads();

    float pacc[4] = {0.f, 0.f, 0.f, 0.f};

    if (active) {
        f32x16 acc[4];
#pragma unroll
        for (int ct = 0; ct < 4; ++ct)
#pragma unroll
            for (int i = 0; i < 16; ++i) acc[ct][i] = 0.0f;

        const unsigned short* wbase = Wt + n32 * WT_STRIDE + hf * 8;

        // consume 8 fp8 fragments of `buf` (decode->bf16) against weight mat m
#define DOMAT(buf, m)                                                          \
        {                                                                      \
            const unsigned short* wm = wbase + (m) * (HID * WT_STRIDE);        \
            _Pragma("unroll")                                                  \
            for (int t = 0; t < 8; ++t) {                                      \
                bf16x8 afr = f8_to_bf16x8(buf[t]);                             \
                _Pragma("unroll")                                              \
                for (int ct = 0; ct < 4; ++ct) {                               \
                    bf16x8 bfr = *(const bf16x8*)(wm + ct * 32 * WT_STRIDE + t * 16); \
                    acc[ct] = __builtin_amdgcn_mfma_f32_32x32x16_bf16(         \
                        afr, bfr, acc[ct], 0, 0, 0);                           \
                }                                                              \
            }                                                                  \
        }
#define LDMAT(buf, srcp)                                                       \
        {                                                                      \
            const uint2* _p = (srcp) + rbase;                                  \
            _Pragma("unroll")                                                  \
            for (int t = 0; t < 8; ++t) buf[t] = _p[t * 2];                    \
        }

        LDMAT(bufB, s1);   // issue mat1 loads
        DOMAT(bufA, 0);    // compute mat0 (hides mat1 latency)
        LDMAT(bufA, s2);   // issue mat2
        DOMAT(bufB, 1);
        LDMAT(bufB, xf8);  // issue mat3 (lin path, fp8 x)
        DOMAT(bufA, 2);
        DOMAT(bufB, 3);
#undef DOMAT
#undef LDMAT

        int node0 = g0 * 32;
#pragma unroll
        for (int reg = 0; reg < 16; ++reg) {
            int row = node0 + (reg & 3) + 8 * (reg >> 2) + 4 * hf;
            float v[4];
            float s = 0.f, q = 0.f;
#pragma unroll
            for (int ct = 0; ct < 4; ++ct) {
                v[ct] = acc[ct][reg] + csh[ct * 32 + n32];
                s += v[ct];
                q += v[ct] * v[ct];
            }
#pragma unroll
            for (int mk = 1; mk < 32; mk <<= 1) {
                s += __shfl_xor(s, mk);
                q += __shfl_xor(q, mk);
            }
            float mu = s * (1.0f / HID);
            float rstd = rsqrtf(q * (1.0f / HID) - mu * mu + LN_EPS);
            if (row < N_NODES) {
#pragma unroll
                for (int ct = 0; ct < 4; ++ct) {
                    int col = ct * 32 + n32;
                    pacc[ct] += (v[ct] - mu) * rstd * csh[HID + col] + csh[2 * HID + col];
                }
            }
        }
    }

#pragma unroll
    for (int ct = 0; ct < 4; ++ct) {
        float t = pacc[ct] + __shfl_xor(pacc[ct], 32);
        if (hf == 0) atomicAdd(&pooled_sh[ct * 32 + n32], t);
    }
    __syncthreads();
    if (threadIdx.x < HID) atomicAdd(&pooled[threadIdx.x], pooled_sh[threadIdx.x]);

    // ---- folded final reduction (last block) ----
    __threadfence();
    __syncthreads();
    if (threadIdx.x == 0)
        lastFlag = (atomicAdd(done, 1) == (int)gridDim.x - 1);
    __syncthreads();
    if (lastFlag && threadIdx.x < 64) {
        int l = threadIdx.x;
        // atomic fetch-add(0) reads take the same coherent path as the writes
        float s = atomicAdd(&pooled[l], 0.0f) * reg_w[l] +
                  atomicAdd(&pooled[64 + l], 0.0f) * reg_w[64 + l];
#pragma unroll
        for (int o = 32; o; o >>= 1) s += __shfl_down(s, o);
        if (l == 0) out[0] = s * (1.0f / N_NODES) + reg_b[0];
    }
}

// ---------------------------------------------------------------------------
extern "C" void kernel_launch(void* const* d_in, const int* in_sizes, int n_in,
                              void* d_out, int out_size, void* d_ws, size_t ws_size,
                              hipStream_t stream) {
    const int* z = (const int*)d_in[0];
    const int* nt = (const int*)d_in[1];
    const int* ei = (const int*)d_in[2];
    const int* et = (const int*)d_in[3];
    const float* z_embed = (const float*)d_in[4];
    const float* enc_w1 = (const float*)d_in[5];
    const float* enc_b1 = (const float*)d_in[6];
    const float* enc_w2 = (const float*)d_in[7];
    const float* enc_b2 = (const float*)d_in[8];
    const float* lin_w = (const float*)d_in[9];
    const float* lin_b = (const float*)d_in[10];
    const float* rel_w = (const float*)d_in[11];
    const float* ln_g = (const float*)d_in[12];
    const float* ln_b = (const float*)d_in[13];
    const float* reg_w = (const float*)d_in[14];
    const float* reg_b = (const float*)d_in[15];
    float* out = (float*)d_out;

    const size_t NHf8 = (size_t)NROWS * HID;  // bytes per fp8 feature plane
    char* p = (char*)d_ws;
    uint2* xf8 = (uint2*)p;                     p += NHf8;   // 6.4 MB
    uint2* s0 = (uint2*)p;                      p += NHf8;   // fp8 means
    uint2* s1 = (uint2*)p;                      p += NHf8;
    uint2* s2 = (uint2*)p;                      p += NHf8;
    unsigned short* wbuf = (unsigned short*)p;  p += (size_t)4 * HID * WT_STRIDE * 2;
    unsigned int* ytab = (unsigned int*)p;      p += (size_t)N_REL * NCOMBO * HID;  // fp8
    float* lintab = (float*)p;                  p += NCOMBO * HID * 4;
    unsigned short* combo = (unsigned short*)p; p += N_NODES * 2;
    float* pooled = (float*)p;                  p += HID * 4;
    int* cnt3 = (int*)p;                        p += N_NODES * 4;
    int* bcnt = (int*)p;                        p += NBKT * 4;
    int* done = (int*)p;                        p += 4;        // adjacent to bcnt
    int* bucket = (int*)p;                      p += (size_t)NBKT * CAP1 * 4;
    int* payload = (int*)p;                     p += (size_t)N_NODES * CAP * 4;

    const int* src = ei;
    const int* dst = ei + N_EDGES;

    hipMemsetAsync(bcnt, 0, (NBKT + 1) * sizeof(int), stream);  // bcnt + done

    // front-end: edge binning || encoder tables || weight prep (one dispatch)
    build_tables_kernel<<<NBKT + NCOMBO + 256, 256, 0, stream>>>(
        src, dst, et, z, nt, z_embed, enc_w1, enc_b1, enc_w2, enc_b2,
        rel_w, lin_w, lin_b, combo, bcnt, bucket, ytab, lintab, wbuf, pooled);

    build2_kernel<<<NBKT, 256, 0, stream>>>(bcnt, bucket, combo, cnt3, payload);

    // layer 1: fused fp8 table-gather + lin + LN -> xf8 (fp8 only)
    gather_ln1_kernel<<<3125, 256, 0, stream>>>(cnt3, payload, (const uint2*)ytab, lintab,
                                                combo, ln_g, ln_b, xf8);
    // layer 2: fp8 gather -> fp8 means; MFMA fused layer (pool + final fold)
    gather3_kernel<<<3125, 256, 0, stream>>>(cnt3, payload, xf8, s0, s1, s2);
    fused_layer_kernel<<<256, 512, 0, stream>>>(
        s0, s1, s2, xf8, (const uint4*)wbuf, lin_b + HID, ln_g + HID, ln_b + HID,
        pooled, reg_w, reg_b, out, done);
}